// Round 7
// baseline (233.309 us; speedup 1.0000x reference)
//
#include <hip/hip_runtime.h>

// GAT layer: N=100000 nodes, E=1.6M edges, IN=128, H=4, F=16 (H*F=64)
// fp32 in/out. 5 dispatches:
//   memset:    gcur[256]+scur[1568] = 0 (contiguous, one call)
//   gemm_att:  h=x@W via bf16 MFMA; att = x@(W@a) folded into 8 extra
//              B-columns. h stored bf16. (bcount tail REMOVED: fixed-
//              capacity regions need no pre-counting.)
//   bscatter:  LDS-staged radix partition -> packed (src<<9|dstloc) ints
//              into FIXED BCAP regions per 512-node bucket; bases via one
//              global atomicAdd(&gcur[b], cnt) per block-bucket (round-6
//              lesson: exact packing cost 2x256-scan/block + bcount pass;
//              all deleted).
//   sliceshuffle: 8 chunks/bucket = 1568 blocks x 256 thr (6.1/CU;
//              round-6 lesson: 196 blocks = 0.77/CU grid-limited, 23us).
//              Ballot-aggregated wave binning into 8 slice regions, ONE
//              global atomic per wave-slice-group (~0.125/edge), order
//              within slice arbitrary (K3 re-sorts).
//   bucket_csr_agg: 1568 blocks (256 thr, one 64-node slice). Exact-range
//              read, LDS counting sort (hist+scan+scatter, 2 int
//              atomics/edge), register-accumulator agg with 4-edge
//              batching: 8-lane group per node, lane q owns features
//              8q..8q+7 + its head's softmax denom. L2-fill-BW-bound at
//              ~3.2 TB/s effective (hmat random gather x 8 XCDs). No
//              float atomics. Inline exp(leakyrelu), no max-shift
//              (softmax shift-inv, |e|<~25 fp32-safe); fused norm+ELU.

#define NEG_SLOPE 0.2f
#define BSHIFT 9            // 512 nodes per bucket
#define BNODES 512
#define CH 2048             // edges per bscatter block (16 KB LDS staging)
#define QNODES 64           // nodes per agg slice
#define BCAP 9216           // bucket region capacity: mean 8192, sd~90 (+11sd)
#define SCAP 1536           // slice region capacity: mean 1024, sd~32 (+16sd)

typedef __bf16 bf16x8 __attribute__((ext_vector_type(8)));
typedef float  f32x4  __attribute__((ext_vector_type(4)));

static __device__ __forceinline__ unsigned f2b(float f) {
    union { float f; unsigned u; } v; v.f = f;
    return (v.u + 0x7fffu + ((v.u >> 16) & 1u)) >> 16;   // RNE
}
static __device__ __forceinline__ float u2f(unsigned u) {
    union { unsigned u32; float f; } v; v.u32 = u; return v.f;
}

// ---------------- K1: h = x@W (bf16 MFMA) + att MFMA ----------------------
__global__ __launch_bounds__(256) void gemm_att_kernel(
    const float* __restrict__ x,       // [N,128]
    const float* __restrict__ W,       // [128,64]
    const float* __restrict__ a_src,   // [4,16]
    const float* __restrict__ a_dst,   // [4,16]
    unsigned short* __restrict__ h_out,// bf16 [N,64]
    float* __restrict__ att_s_o,       // [N,4]
    float* __restrict__ att_d_o,       // [N,4]
    int N)
{
    __shared__ bf16x8 Wswz[20][64];    // 20 KB
    int t = threadIdx.x;

    // ---- W swizzle ----
    for (int i = t; i < 8192; i += 256) {            // W[k][n], coalesced
        int k = i >> 6, n = i & 63;
        __bf16* dp = (__bf16*)&Wswz[((n >> 4) << 2) | (k >> 5)]
                                   [(((k >> 3) & 3) << 4) | (n & 15)];
        dp[k & 7] = (__bf16)W[i];
    }
    // ---- ws/wd fold: entry 16+tt, cols 0..7 = [ws|wd], cols 8..15 = 0 ----
    for (int i = t; i < 1024; i += 256) {            // k(128) x c7(8)
        int k = i >> 3, c7 = i & 7;
        int hd = c7 & 3;
        const float* aa = (c7 < 4) ? a_src : a_dst;
        float sum = 0.f;
        #pragma unroll
        for (int f = 0; f < 16; ++f)
            sum = fmaf(W[k * 64 + hd * 16 + f], aa[hd * 16 + f], sum);
        __bf16* dp = (__bf16*)&Wswz[16 + (k >> 5)][(((k >> 3) & 3) << 4) | c7];
        dp[k & 7] = (__bf16)sum;
        __bf16* dz = (__bf16*)&Wswz[16 + (k >> 5)][(((k >> 3) & 3) << 4) | (8 + c7)];
        dz[k & 7] = (__bf16)0.f;
    }
    __syncthreads();

    int wave = t >> 6;
    int lane = t & 63;
    int col = lane & 15, quad = lane >> 4;
    int node_base = (blockIdx.x * 4 + wave) * 16;
    int arow = min(node_base + col, N - 1);
    const float* xp = x + arow * 128;

    bf16x8 af[4];
    #pragma unroll
    for (int tt = 0; tt < 4; ++tt) {
        float4 xa = *(const float4*)(xp + tt * 32 + quad * 8);
        float4 xb = *(const float4*)(xp + tt * 32 + quad * 8 + 4);
        bf16x8 f;
        f[0] = (__bf16)xa.x; f[1] = (__bf16)xa.y;
        f[2] = (__bf16)xa.z; f[3] = (__bf16)xa.w;
        f[4] = (__bf16)xb.x; f[5] = (__bf16)xb.y;
        f[6] = (__bf16)xb.z; f[7] = (__bf16)xb.w;
        af[tt] = f;
    }

    f32x4 acc[4], accA;
    #pragma unroll
    for (int cb = 0; cb < 4; ++cb) {
        acc[cb] = (f32x4){0.f, 0.f, 0.f, 0.f};
        #pragma unroll
        for (int tt = 0; tt < 4; ++tt)
            acc[cb] = __builtin_amdgcn_mfma_f32_16x16x32_bf16(
                af[tt], Wswz[(cb << 2) | tt][lane], acc[cb], 0, 0, 0);
    }
    accA = (f32x4){0.f, 0.f, 0.f, 0.f};
    #pragma unroll
    for (int tt = 0; tt < 4; ++tt)
        accA = __builtin_amdgcn_mfma_f32_16x16x32_bf16(
            af[tt], Wswz[16 + tt][lane], accA, 0, 0, 0);

    // h store: scalar bf16 per (cb,r)
    #pragma unroll
    for (int cb = 0; cb < 4; ++cb) {
        #pragma unroll
        for (int r = 0; r < 4; ++r) {
            int node = node_base + quad * 4 + r;
            if (node < N)
                h_out[node * 64 + cb * 16 + col] = (unsigned short)f2b(acc[cb][r]);
        }
    }
    // att store from accA: D col<4 -> att_s head=col, col 4..7 -> att_d
    if (col < 8) {
        #pragma unroll
        for (int r = 0; r < 4; ++r) {
            int node = node_base + quad * 4 + r;
            if (node < N) {
                if (col < 4) att_s_o[(node << 2) | col] = accA[r];
                else         att_d_o[(node << 2) | (col - 4)] = accA[r];
            }
        }
    }
}

// ---------------- K2: LDS-staged radix partition, fixed-capacity ----------
// Stage CH edges by 512-node bucket (local hist+scan for coalesced runs),
// reserve per-bucket space with ONE global atomicAdd per block-bucket,
// write ~10-edge runs into pairs[b*BCAP + base ...]. No pre-count pass,
// no global scan.
__global__ __launch_bounds__(256) void bscatter_kernel(
    const int* __restrict__ src, const int* __restrict__ dst,
    int* __restrict__ gcur, int* __restrict__ pairs, int E)
{
    __shared__ int cnt[256], lo[256], gpos[256], cur[256], sm[256];
    __shared__ int2 staged[CH];        // .x = packed (s<<9|dloc), .y = bucket
    int t = threadIdx.x;
    int base = blockIdx.x * CH;
    int nloc = min(CH, E - base);

    cnt[t] = 0;
    __syncthreads();
    for (int i = t; i < nloc; i += 256)
        atomicAdd(&cnt[dst[base + i] >> BSHIFT], 1);
    __syncthreads();

    int v = cnt[t];
    sm[t] = v;
    __syncthreads();
    #pragma unroll
    for (int off = 1; off < 256; off <<= 1) {
        int u = (t >= off) ? sm[t - off] : 0;
        __syncthreads();
        sm[t] += u;
        __syncthreads();
    }
    lo[t] = sm[t] - v;
    cur[t] = lo[t];
    gpos[t] = (v > 0) ? t * BCAP + atomicAdd(&gcur[t], v) : 0;
    __syncthreads();

    for (int i = t; i < nloc; i += 256) {
        int d = dst[base + i];
        int s = src[base + i];
        int b = d >> BSHIFT;
        int k = atomicAdd(&cur[b], 1);
        staged[k] = make_int2((s << BSHIFT) | (d & (BNODES - 1)), b);
    }
    __syncthreads();

    for (int i = t; i < nloc; i += 256) {
        int2 p = staged[i];
        int pos = gpos[p.y] + (i - lo[p.y]);
        if (pos < (p.y + 1) * BCAP)          // capacity guard (never fires)
            pairs[pos] = p.x;
    }
}

// ---------------- K2b: bucket -> 8 slice regions (ballot-aggregated) ------
// 8 chunks per bucket = 1568 blocks x 256 thr (6.1 blocks/CU). Per
// 64-edge wave iteration: 8 ballots; leader lane of each slice-group does
// ONE global atomicAdd on scur; rank = popc(mask & below). Writes
// pairs2[(b*8+sl)*SCAP + pos]; scur doubles as final slice count for K3.
__global__ __launch_bounds__(256) void sliceshuffle_kernel(
    const int* __restrict__ pairs, const int* __restrict__ gcur,
    int* __restrict__ pairs2, int* __restrict__ scur)
{
    int blk = blockIdx.x, t = threadIdx.x;
    int b = blk >> 3, chunk = blk & 7;
    int cnt = min(gcur[b], BCAP);
    int clo = (cnt * chunk) >> 3;
    int chi = (cnt * (chunk + 1)) >> 3;
    int lane = t & 63;
    unsigned long long below = (lane == 0) ? 0ull : ((~0ull) >> (64 - lane));
    const int* pb = pairs + (size_t)b * BCAP;

    for (int i = clo + t; i < chi; i += 256) {
        int p = pb[i];
        int sl = (p >> 6) & 7;       // dloc bits 6..8
        int pos = 0;
        #pragma unroll
        for (int s = 0; s < 8; ++s) {
            unsigned long long m = __ballot(sl == s);
            if (sl == s) {
                int rank = __popcll(m & below);
                int b0 = 0;
                if (rank == 0)
                    b0 = atomicAdd(&scur[(b << 3) | s], (int)__popcll(m));
                b0 = __shfl(b0, (int)(__ffsll((long long)m) - 1), 64);
                pos = b0 + rank;
            }
        }
        if (pos < SCAP)
            pairs2[(size_t)((b << 3) | sl) * SCAP + pos] = p;
    }
}

// ---------------- K3: per-slice LDS counting-sort + register agg ----------
// 1568 blocks (256 thr, 64 nodes); exact-range read of its slice from
// pairs2, hist -> scan -> scatter into sorted[] (2 int atomics/edge),
// then 8-lane group per node, 4-edge batched serial accumulation in
// registers, fused normalize+ELU store.
__global__ __launch_bounds__(256, 8) void bucket_csr_agg_kernel(
    const int* __restrict__ pairs2,          // [1568*SCAP] slice regions
    const int* __restrict__ scur,            // [1568] slice edge counts
    const float* __restrict__ att_s,         // [N,4]
    const float* __restrict__ att_d,         // [N,4]
    const unsigned short* __restrict__ hmat, // bf16 [N,64]
    float* __restrict__ out,                 // [N,64]
    int N)
{
    __shared__ int sorted[SCAP];             // src ids, node-sorted (6 KB)
    __shared__ int cnt[QNODES], rs[QNODES + 1], cur[QNODES], sm[QNODES];
    __shared__ float attd[QNODES * 4];

    int blk = blockIdx.x, t = threadIdx.x;
    int b = blk >> 3, s8 = blk & 7;
    int node_lo = (b << BSHIFT) + (s8 << 6);
    if (node_lo >= N) return;
    int nn = min(QNODES, N - node_lo);

    int ebase = blk * SCAP;
    int ecnt  = min(scur[blk], SCAP);

    if (t < QNODES) cnt[t] = 0;
    // att_d for this slice -> LDS (coalesced)
    for (int i = t; i < (nn << 2); i += 256)
        attd[i] = att_d[(node_lo << 2) + i];
    __syncthreads();

    // histogram node-within-slice
    for (int i = t; i < ecnt; i += 256)
        atomicAdd(&cnt[pairs2[ebase + i] & (QNODES - 1)], 1);
    __syncthreads();

    // exclusive scan (64 bins) -> rs; cur = scatter cursors
    int v = (t < QNODES) ? cnt[t] : 0;
    if (t < QNODES) sm[t] = v;
    __syncthreads();
    #pragma unroll
    for (int off = 1; off < QNODES; off <<= 1) {
        int u = (t >= off && t < QNODES) ? sm[t - off] : 0;
        __syncthreads();
        if (t < QNODES) sm[t] += u;
        __syncthreads();
    }
    if (t < QNODES) {
        int x = sm[t] - v; rs[t] = x; cur[t] = x;
        if (t == QNODES - 1) rs[QNODES] = sm[t];   // slice total
    }
    __syncthreads();

    // scatter src ids into node-sorted order (re-read hits L1/L2)
    for (int i = t; i < ecnt; i += 256) {
        int p = pairs2[ebase + i];
        int k = atomicAdd(&cur[p & (QNODES - 1)], 1);
        if (k < SCAP) sorted[k] = p >> BSHIFT;
    }
    __syncthreads();

    // aggregate: 32 groups of 8 lanes, 2 passes over 64 nodes
    int q = t & 7;            // feature octet: features 8q..8q+7
    int h = q >> 1;           // head
    int nclamp = N - 1;       // OOB hardening (impossible SCAP overflow)

    for (int pass = 0; pass < 2; ++pass) {
        int node = (pass << 5) + (t >> 3);
        if (node >= nn) continue;
        int beg = rs[node];
        int deg = rs[node + 1] - beg;
        float ad = attd[(node << 2) | h];

        float a0 = 0.f, a1 = 0.f, a2 = 0.f, a3 = 0.f;
        float a4 = 0.f, a5 = 0.f, a6 = 0.f, a7 = 0.f, l = 0.f;
        int d1 = deg - 1;
        for (int e0 = 0; e0 < deg; e0 += 4) {
            int s0 = min(sorted[beg + min(e0 + 0, d1)], nclamp);
            int s1 = min(sorted[beg + min(e0 + 1, d1)], nclamp);
            int s2 = min(sorted[beg + min(e0 + 2, d1)], nclamp);
            int s3 = min(sorted[beg + min(e0 + 3, d1)], nclamp);
            float t0 = att_s[(s0 << 2) | h];
            float t1 = att_s[(s1 << 2) | h];
            float t2 = att_s[(s2 << 2) | h];
            float t3 = att_s[(s3 << 2) | h];
            uint4 hp0 = *(const uint4*)(hmat + (s0 << 6) + (q << 3));
            uint4 hp1 = *(const uint4*)(hmat + (s1 << 6) + (q << 3));
            uint4 hp2 = *(const uint4*)(hmat + (s2 << 6) + (q << 3));
            uint4 hp3 = *(const uint4*)(hmat + (s3 << 6) + (q << 3));
            float av0 = t0 + ad; av0 = fmaxf(av0, NEG_SLOPE * av0);
            float av1 = t1 + ad; av1 = fmaxf(av1, NEG_SLOPE * av1);
            float av2 = t2 + ad; av2 = fmaxf(av2, NEG_SLOPE * av2);
            float av3 = t3 + ad; av3 = fmaxf(av3, NEG_SLOPE * av3);
            float w0 = __expf(av0);
            float w1 = (e0 + 1 < deg) ? __expf(av1) : 0.f;
            float w2 = (e0 + 2 < deg) ? __expf(av2) : 0.f;
            float w3 = (e0 + 3 < deg) ? __expf(av3) : 0.f;
            l += w0 + w1 + w2 + w3;
            a0 = fmaf(w0, u2f(hp0.x << 16), a0);
            a1 = fmaf(w0, u2f(hp0.x & 0xffff0000u), a1);
            a2 = fmaf(w0, u2f(hp0.y << 16), a2);
            a3 = fmaf(w0, u2f(hp0.y & 0xffff0000u), a3);
            a4 = fmaf(w0, u2f(hp0.z << 16), a4);
            a5 = fmaf(w0, u2f(hp0.z & 0xffff0000u), a5);
            a6 = fmaf(w0, u2f(hp0.w << 16), a6);
            a7 = fmaf(w0, u2f(hp0.w & 0xffff0000u), a7);
            a0 = fmaf(w1, u2f(hp1.x << 16), a0);
            a1 = fmaf(w1, u2f(hp1.x & 0xffff0000u), a1);
            a2 = fmaf(w1, u2f(hp1.y << 16), a2);
            a3 = fmaf(w1, u2f(hp1.y & 0xffff0000u), a3);
            a4 = fmaf(w1, u2f(hp1.z << 16), a4);
            a5 = fmaf(w1, u2f(hp1.z & 0xffff0000u), a5);
            a6 = fmaf(w1, u2f(hp1.w << 16), a6);
            a7 = fmaf(w1, u2f(hp1.w & 0xffff0000u), a7);
            a0 = fmaf(w2, u2f(hp2.x << 16), a0);
            a1 = fmaf(w2, u2f(hp2.x & 0xffff0000u), a1);
            a2 = fmaf(w2, u2f(hp2.y << 16), a2);
            a3 = fmaf(w2, u2f(hp2.y & 0xffff0000u), a3);
            a4 = fmaf(w2, u2f(hp2.z << 16), a4);
            a5 = fmaf(w2, u2f(hp2.z & 0xffff0000u), a5);
            a6 = fmaf(w2, u2f(hp2.w << 16), a6);
            a7 = fmaf(w2, u2f(hp2.w & 0xffff0000u), a7);
            a0 = fmaf(w3, u2f(hp3.x << 16), a0);
            a1 = fmaf(w3, u2f(hp3.x & 0xffff0000u), a1);
            a2 = fmaf(w3, u2f(hp3.y << 16), a2);
            a3 = fmaf(w3, u2f(hp3.y & 0xffff0000u), a3);
            a4 = fmaf(w3, u2f(hp3.z << 16), a4);
            a5 = fmaf(w3, u2f(hp3.z & 0xffff0000u), a5);
            a6 = fmaf(w3, u2f(hp3.w << 16), a6);
            a7 = fmaf(w3, u2f(hp3.w & 0xffff0000u), a7);
        }

        float rl = 1.0f / (l + 1e-16f);
        float4 v0, v1;
        v0.x = a0 * rl; v0.x = (v0.x > 0.f) ? v0.x : (__expf(v0.x) - 1.f);
        v0.y = a1 * rl; v0.y = (v0.y > 0.f) ? v0.y : (__expf(v0.y) - 1.f);
        v0.z = a2 * rl; v0.z = (v0.z > 0.f) ? v0.z : (__expf(v0.z) - 1.f);
        v0.w = a3 * rl; v0.w = (v0.w > 0.f) ? v0.w : (__expf(v0.w) - 1.f);
        v1.x = a4 * rl; v1.x = (v1.x > 0.f) ? v1.x : (__expf(v1.x) - 1.f);
        v1.y = a5 * rl; v1.y = (v1.y > 0.f) ? v1.y : (__expf(v1.y) - 1.f);
        v1.z = a6 * rl; v1.z = (v1.z > 0.f) ? v1.z : (__expf(v1.z) - 1.f);
        v1.w = a7 * rl; v1.w = (v1.w > 0.f) ? v1.w : (__expf(v1.w) - 1.f);
        float* op = out + ((size_t)(node_lo + node) << 6) + (q << 3);
        *(float4*)op = v0;
        *(float4*)(op + 4) = v1;
    }
}

extern "C" void kernel_launch(void* const* d_in, const int* in_sizes, int n_in,
                              void* d_out, int out_size, void* d_ws, size_t ws_size,
                              hipStream_t stream) {
    const float* x     = (const float*)d_in[0];
    const int*   ei    = (const int*)d_in[1];
    const float* W     = (const float*)d_in[2];
    const float* a_src = (const float*)d_in[3];
    const float* a_dst = (const float*)d_in[4];

    int N = in_sizes[0] / 128;
    int E = in_sizes[1] / 2;
    const int* src = ei;
    const int* dst = ei + E;
    int nb = (N + BNODES - 1) / BNODES;       // 196 buckets

    char* ws = (char*)d_ws;
    size_t off = 0;
    unsigned short* hmat = (unsigned short*)(ws + off); off += (size_t)N * 64 * 2; // 12.8 MB
    float* att_s = (float*)(ws + off);  off += (size_t)N * 4 * 4;
    float* att_d = (float*)(ws + off);  off += (size_t)N * 4 * 4;
    int* pairs    = (int*)(ws + off);   off += (size_t)nb * BCAP * 4;      // 7.2 MB
    int* pairs2   = (int*)(ws + off);   off += (size_t)nb * 8 * SCAP * 4;  // 9.6 MB
    int* gcur     = (int*)(ws + off);   off += 256 * 4;                    // zeroed
    int* scur     = (int*)(ws + off);   off += (size_t)nb * 8 * 4;         // zeroed

    hipMemsetAsync(gcur, 0, (256 + nb * 8) * 4, stream);  // gcur+scur contiguous

    int gemmBlocks = (N + 63) / 64;           // 1563
    gemm_att_kernel<<<gemmBlocks, 256, 0, stream>>>(
        x, W, a_src, a_dst, hmat, att_s, att_d, N);

    int blocksS = (E + CH - 1) / CH;          // 782
    bscatter_kernel<<<blocksS, 256, 0, stream>>>(src, dst, gcur, pairs, E);

    sliceshuffle_kernel<<<nb * 8, 256, 0, stream>>>(pairs, gcur, pairs2, scur);

    bucket_csr_agg_kernel<<<nb * 8, 256, 0, stream>>>(
        pairs2, scur, att_s, att_d, hmat, (float*)d_out, N);
}

// Round 8
// 201.548 us; speedup vs baseline: 1.1576x; 1.1576x over previous
//
#include <hip/hip_runtime.h>

// GAT layer: N=100000 nodes, E=1.6M edges, IN=128, H=4, F=16 (H*F=64)
// fp32 in/out. 4 dispatches:
//   gemm_att:  h=x@W via bf16 MFMA; att = x@(W@a) folded into 8 extra
//              B-columns. h stored bf16. Block 0 zeroes gcur (memset
//              dispatch removed; stream order covers bscatter).
//   bscatter:  LDS-staged radix partition -> packed (src<<9|dstloc) ints
//              into FIXED BCAP regions per 512-node bucket; bases via one
//              global atomicAdd(&gcur[b], cnt) per block-bucket.
//   sliceshuffle: 8 chunks/bucket = 1568 blocks x 256 thr. Single pass,
//              ballot-aggregated LDS cursors, writes PRIVATE per-
//              (slice,chunk) sub-regions (SCAPC=256) + scnt counts.
//              ZERO global atomics (round-7 lesson: returning global
//              atomics on a shared cache line from 8 XCDs = 49us;
//              round-1 lesson: LDS atomics ~3.2cyc/lane-op, so ballot-
//              aggregate to 0.125/edge).
//   bucket_csr_agg: 1568 blocks (256 thr, one 64-node slice). Reads its
//              slice as 8 short contiguous segments, LDS counting sort
//              (hist+scan+scatter, 2 int atomics/edge), register-
//              accumulator agg with 4-edge batching: 8-lane group per
//              node, lane q owns features 8q..8q+7 + its head's softmax
//              denom. L2-fill-BW-bound (~3.2 TB/s effective; hmat random
//              gather x 8 XCDs). No float atomics. Inline exp(leakyrelu),
//              no max-shift (softmax shift-inv, |e|<~25 fp32-safe);
//              fused normalize+ELU epilogue.

#define NEG_SLOPE 0.2f
#define BSHIFT 9            // 512 nodes per bucket
#define BNODES 512
#define CH 2048             // edges per bscatter block (16 KB LDS staging)
#define QNODES 64           // nodes per agg slice
#define BCAP 9216           // bucket region capacity: mean 8192, sd~90 (+11sd)
#define SCAP 1536           // LDS sorted[] capacity: mean 1024, sd~32 (+16sd)
#define SCAPC 256           // per-(slice,chunk) sub-region: mean 128, sd~11

typedef __bf16 bf16x8 __attribute__((ext_vector_type(8)));
typedef float  f32x4  __attribute__((ext_vector_type(4)));

static __device__ __forceinline__ unsigned f2b(float f) {
    union { float f; unsigned u; } v; v.f = f;
    return (v.u + 0x7fffu + ((v.u >> 16) & 1u)) >> 16;   // RNE
}
static __device__ __forceinline__ float u2f(unsigned u) {
    union { unsigned u32; float f; } v; v.u32 = u; return v.f;
}

// ---------------- K1: h = x@W (bf16 MFMA) + att MFMA ----------------------
__global__ __launch_bounds__(256) void gemm_att_kernel(
    const float* __restrict__ x,       // [N,128]
    const float* __restrict__ W,       // [128,64]
    const float* __restrict__ a_src,   // [4,16]
    const float* __restrict__ a_dst,   // [4,16]
    unsigned short* __restrict__ h_out,// bf16 [N,64]
    float* __restrict__ att_s_o,       // [N,4]
    float* __restrict__ att_d_o,       // [N,4]
    int* __restrict__ gcur,            // [256] zeroed here (block 0)
    int N)
{
    __shared__ bf16x8 Wswz[20][64];    // 20 KB
    int t = threadIdx.x;

    if (blockIdx.x == 0) gcur[t] = 0;  // replaces memset dispatch

    // ---- W swizzle ----
    for (int i = t; i < 8192; i += 256) {            // W[k][n], coalesced
        int k = i >> 6, n = i & 63;
        __bf16* dp = (__bf16*)&Wswz[((n >> 4) << 2) | (k >> 5)]
                                   [(((k >> 3) & 3) << 4) | (n & 15)];
        dp[k & 7] = (__bf16)W[i];
    }
    // ---- ws/wd fold: entry 16+tt, cols 0..7 = [ws|wd], cols 8..15 = 0 ----
    for (int i = t; i < 1024; i += 256) {            // k(128) x c7(8)
        int k = i >> 3, c7 = i & 7;
        int hd = c7 & 3;
        const float* aa = (c7 < 4) ? a_src : a_dst;
        float sum = 0.f;
        #pragma unroll
        for (int f = 0; f < 16; ++f)
            sum = fmaf(W[k * 64 + hd * 16 + f], aa[hd * 16 + f], sum);
        __bf16* dp = (__bf16*)&Wswz[16 + (k >> 5)][(((k >> 3) & 3) << 4) | c7];
        dp[k & 7] = (__bf16)sum;
        __bf16* dz = (__bf16*)&Wswz[16 + (k >> 5)][(((k >> 3) & 3) << 4) | (8 + c7)];
        dz[k & 7] = (__bf16)0.f;
    }
    __syncthreads();

    int wave = t >> 6;
    int lane = t & 63;
    int col = lane & 15, quad = lane >> 4;
    int node_base = (blockIdx.x * 4 + wave) * 16;
    int arow = min(node_base + col, N - 1);
    const float* xp = x + arow * 128;

    bf16x8 af[4];
    #pragma unroll
    for (int tt = 0; tt < 4; ++tt) {
        float4 xa = *(const float4*)(xp + tt * 32 + quad * 8);
        float4 xb = *(const float4*)(xp + tt * 32 + quad * 8 + 4);
        bf16x8 f;
        f[0] = (__bf16)xa.x; f[1] = (__bf16)xa.y;
        f[2] = (__bf16)xa.z; f[3] = (__bf16)xa.w;
        f[4] = (__bf16)xb.x; f[5] = (__bf16)xb.y;
        f[6] = (__bf16)xb.z; f[7] = (__bf16)xb.w;
        af[tt] = f;
    }

    f32x4 acc[4], accA;
    #pragma unroll
    for (int cb = 0; cb < 4; ++cb) {
        acc[cb] = (f32x4){0.f, 0.f, 0.f, 0.f};
        #pragma unroll
        for (int tt = 0; tt < 4; ++tt)
            acc[cb] = __builtin_amdgcn_mfma_f32_16x16x32_bf16(
                af[tt], Wswz[(cb << 2) | tt][lane], acc[cb], 0, 0, 0);
    }
    accA = (f32x4){0.f, 0.f, 0.f, 0.f};
    #pragma unroll
    for (int tt = 0; tt < 4; ++tt)
        accA = __builtin_amdgcn_mfma_f32_16x16x32_bf16(
            af[tt], Wswz[16 + tt][lane], accA, 0, 0, 0);

    // h store: scalar bf16 per (cb,r)
    #pragma unroll
    for (int cb = 0; cb < 4; ++cb) {
        #pragma unroll
        for (int r = 0; r < 4; ++r) {
            int node = node_base + quad * 4 + r;
            if (node < N)
                h_out[node * 64 + cb * 16 + col] = (unsigned short)f2b(acc[cb][r]);
        }
    }
    // att store from accA: D col<4 -> att_s head=col, col 4..7 -> att_d
    if (col < 8) {
        #pragma unroll
        for (int r = 0; r < 4; ++r) {
            int node = node_base + quad * 4 + r;
            if (node < N) {
                if (col < 4) att_s_o[(node << 2) | col] = accA[r];
                else         att_d_o[(node << 2) | (col - 4)] = accA[r];
            }
        }
    }
}

// ---------------- K2: LDS-staged radix partition, fixed-capacity ----------
__global__ __launch_bounds__(256) void bscatter_kernel(
    const int* __restrict__ src, const int* __restrict__ dst,
    int* __restrict__ gcur, int* __restrict__ pairs, int E)
{
    __shared__ int cnt[256], lo[256], gpos[256], cur[256], sm[256];
    __shared__ int2 staged[CH];        // .x = packed (s<<9|dloc), .y = bucket
    int t = threadIdx.x;
    int base = blockIdx.x * CH;
    int nloc = min(CH, E - base);

    cnt[t] = 0;
    __syncthreads();
    for (int i = t; i < nloc; i += 256)
        atomicAdd(&cnt[dst[base + i] >> BSHIFT], 1);
    __syncthreads();

    int v = cnt[t];
    sm[t] = v;
    __syncthreads();
    #pragma unroll
    for (int off = 1; off < 256; off <<= 1) {
        int u = (t >= off) ? sm[t - off] : 0;
        __syncthreads();
        sm[t] += u;
        __syncthreads();
    }
    lo[t] = sm[t] - v;
    cur[t] = lo[t];
    gpos[t] = (v > 0) ? t * BCAP + atomicAdd(&gcur[t], v) : 0;
    __syncthreads();

    for (int i = t; i < nloc; i += 256) {
        int d = dst[base + i];
        int s = src[base + i];
        int b = d >> BSHIFT;
        int k = atomicAdd(&cur[b], 1);
        staged[k] = make_int2((s << BSHIFT) | (d & (BNODES - 1)), b);
    }
    __syncthreads();

    for (int i = t; i < nloc; i += 256) {
        int2 p = staged[i];
        int pos = gpos[p.y] + (i - lo[p.y]);
        if (pos < (p.y + 1) * BCAP)          // capacity guard (never fires)
            pairs[pos] = p.x;
    }
}

// ---------------- K2b: bucket -> private (slice,chunk) sub-regions --------
// 1568 blocks x 256 thr, single pass, LDS cursors only. Per 64-edge wave
// iteration: 8 ballots; leader lane of each slice-group bumps LDS cur8
// once; rank = popc(mask & below). Writes
// pairs2[((b*8+sl)*8+chunk)*SCAPC + pos]; scnt[(b*8+sl)*8+chunk] = count.
__global__ __launch_bounds__(256) void sliceshuffle_kernel(
    const int* __restrict__ pairs, const int* __restrict__ gcur,
    int* __restrict__ pairs2, int* __restrict__ scnt)
{
    __shared__ int cur8[8];
    int blk = blockIdx.x, t = threadIdx.x;
    int b = blk >> 3, chunk = blk & 7;
    int cnt = min(gcur[b], BCAP);
    int clo = (cnt * chunk) >> 3;
    int chi = (cnt * (chunk + 1)) >> 3;
    int lane = t & 63;
    unsigned long long below = (lane == 0) ? 0ull : ((~0ull) >> (64 - lane));
    const int* pb = pairs + (size_t)b * BCAP;
    if (t < 8) cur8[t] = 0;
    __syncthreads();

    for (int i = clo + t; i < chi; i += 256) {
        int p = pb[i];
        int sl = (p >> 6) & 7;       // dloc bits 6..8
        int pos = 0;
        #pragma unroll
        for (int s = 0; s < 8; ++s) {
            unsigned long long m = __ballot(sl == s);
            if (sl == s) {
                int rank = __popcll(m & below);
                int b0 = 0;
                if (rank == 0) b0 = atomicAdd(&cur8[s], (int)__popcll(m));
                b0 = __shfl(b0, (int)(__ffsll((long long)m) - 1), 64);
                pos = b0 + rank;
            }
        }
        if (pos < SCAPC)
            pairs2[((size_t)((((b << 3) | sl) << 3) | chunk)) * SCAPC + pos] = p;
    }
    __syncthreads();
    if (t < 8) scnt[((((b << 3) | t) << 3) | chunk)] = min(cur8[t], SCAPC);
}

// ---------------- K3: per-slice LDS counting-sort + register agg ----------
// 1568 blocks (256 thr, 64 nodes); reads its slice as 8 contiguous
// segments (counts in scnt), hist -> scan -> scatter into sorted[]
// (2 int atomics/edge), then 8-lane group per node, 4-edge batched
// serial accumulation in registers, fused normalize+ELU store.
__global__ __launch_bounds__(256, 8) void bucket_csr_agg_kernel(
    const int* __restrict__ pairs2,          // [nb*64*SCAPC] sub-regions
    const int* __restrict__ scnt,            // [nb*64] sub-region counts
    const float* __restrict__ att_s,         // [N,4]
    const float* __restrict__ att_d,         // [N,4]
    const unsigned short* __restrict__ hmat, // bf16 [N,64]
    float* __restrict__ out,                 // [N,64]
    int N)
{
    __shared__ int sorted[SCAP];             // src ids, node-sorted (6 KB)
    __shared__ int cnt[QNODES], rs[QNODES + 1], cur[QNODES], sm[QNODES];
    __shared__ int scn[8];
    __shared__ float attd[QNODES * 4];

    int blk = blockIdx.x, t = threadIdx.x;
    int b = blk >> 3, s8 = blk & 7;
    int node_lo = (b << BSHIFT) + (s8 << 6);
    if (node_lo >= N) return;
    int nn = min(QNODES, N - node_lo);

    if (t < QNODES) cnt[t] = 0;
    if (t < 8) scn[t] = scnt[(blk << 3) | t];
    // att_d for this slice -> LDS (coalesced)
    for (int i = t; i < (nn << 2); i += 256)
        attd[i] = att_d[(node_lo << 2) + i];
    __syncthreads();

    // histogram node-within-slice over 8 segments
    const int* sbase = pairs2 + ((size_t)blk << 3) * SCAPC;
    #pragma unroll
    for (int c = 0; c < 8; ++c) {
        int cn = scn[c];
        const int* seg = sbase + c * SCAPC;
        for (int i = t; i < cn; i += 256)
            atomicAdd(&cnt[seg[i] & (QNODES - 1)], 1);
    }
    __syncthreads();

    // exclusive scan (64 bins) -> rs; cur = scatter cursors
    int v = (t < QNODES) ? cnt[t] : 0;
    if (t < QNODES) sm[t] = v;
    __syncthreads();
    #pragma unroll
    for (int off = 1; off < QNODES; off <<= 1) {
        int u = (t >= off && t < QNODES) ? sm[t - off] : 0;
        __syncthreads();
        if (t < QNODES) sm[t] += u;
        __syncthreads();
    }
    if (t < QNODES) {
        int x = sm[t] - v; rs[t] = x; cur[t] = x;
        if (t == QNODES - 1) rs[QNODES] = sm[t];   // slice total
    }
    __syncthreads();

    // scatter src ids into node-sorted order (segments are L2-hot)
    #pragma unroll
    for (int c = 0; c < 8; ++c) {
        int cn = scn[c];
        const int* seg = sbase + c * SCAPC;
        for (int i = t; i < cn; i += 256) {
            int p = seg[i];
            int k = atomicAdd(&cur[p & (QNODES - 1)], 1);
            if (k < SCAP) sorted[k] = p >> BSHIFT;
        }
    }
    __syncthreads();

    // aggregate: 32 groups of 8 lanes, 2 passes over 64 nodes
    int q = t & 7;            // feature octet: features 8q..8q+7
    int h = q >> 1;           // head
    int nclamp = N - 1;       // OOB hardening (impossible SCAP overflow)

    for (int pass = 0; pass < 2; ++pass) {
        int node = (pass << 5) + (t >> 3);
        if (node >= nn) continue;
        int beg = rs[node];
        int deg = rs[node + 1] - beg;
        float ad = attd[(node << 2) | h];

        float a0 = 0.f, a1 = 0.f, a2 = 0.f, a3 = 0.f;
        float a4 = 0.f, a5 = 0.f, a6 = 0.f, a7 = 0.f, l = 0.f;
        int d1 = deg - 1;
        for (int e0 = 0; e0 < deg; e0 += 4) {
            int s0 = min(sorted[beg + min(e0 + 0, d1)], nclamp);
            int s1 = min(sorted[beg + min(e0 + 1, d1)], nclamp);
            int s2 = min(sorted[beg + min(e0 + 2, d1)], nclamp);
            int s3 = min(sorted[beg + min(e0 + 3, d1)], nclamp);
            float t0 = att_s[(s0 << 2) | h];
            float t1 = att_s[(s1 << 2) | h];
            float t2 = att_s[(s2 << 2) | h];
            float t3 = att_s[(s3 << 2) | h];
            uint4 hp0 = *(const uint4*)(hmat + (s0 << 6) + (q << 3));
            uint4 hp1 = *(const uint4*)(hmat + (s1 << 6) + (q << 3));
            uint4 hp2 = *(const uint4*)(hmat + (s2 << 6) + (q << 3));
            uint4 hp3 = *(const uint4*)(hmat + (s3 << 6) + (q << 3));
            float av0 = t0 + ad; av0 = fmaxf(av0, NEG_SLOPE * av0);
            float av1 = t1 + ad; av1 = fmaxf(av1, NEG_SLOPE * av1);
            float av2 = t2 + ad; av2 = fmaxf(av2, NEG_SLOPE * av2);
            float av3 = t3 + ad; av3 = fmaxf(av3, NEG_SLOPE * av3);
            float w0 = __expf(av0);
            float w1 = (e0 + 1 < deg) ? __expf(av1) : 0.f;
            float w2 = (e0 + 2 < deg) ? __expf(av2) : 0.f;
            float w3 = (e0 + 3 < deg) ? __expf(av3) : 0.f;
            l += w0 + w1 + w2 + w3;
            a0 = fmaf(w0, u2f(hp0.x << 16), a0);
            a1 = fmaf(w0, u2f(hp0.x & 0xffff0000u), a1);
            a2 = fmaf(w0, u2f(hp0.y << 16), a2);
            a3 = fmaf(w0, u2f(hp0.y & 0xffff0000u), a3);
            a4 = fmaf(w0, u2f(hp0.z << 16), a4);
            a5 = fmaf(w0, u2f(hp0.z & 0xffff0000u), a5);
            a6 = fmaf(w0, u2f(hp0.w << 16), a6);
            a7 = fmaf(w0, u2f(hp0.w & 0xffff0000u), a7);
            a0 = fmaf(w1, u2f(hp1.x << 16), a0);
            a1 = fmaf(w1, u2f(hp1.x & 0xffff0000u), a1);
            a2 = fmaf(w1, u2f(hp1.y << 16), a2);
            a3 = fmaf(w1, u2f(hp1.y & 0xffff0000u), a3);
            a4 = fmaf(w1, u2f(hp1.z << 16), a4);
            a5 = fmaf(w1, u2f(hp1.z & 0xffff0000u), a5);
            a6 = fmaf(w1, u2f(hp1.w << 16), a6);
            a7 = fmaf(w1, u2f(hp1.w & 0xffff0000u), a7);
            a0 = fmaf(w2, u2f(hp2.x << 16), a0);
            a1 = fmaf(w2, u2f(hp2.x & 0xffff0000u), a1);
            a2 = fmaf(w2, u2f(hp2.y << 16), a2);
            a3 = fmaf(w2, u2f(hp2.y & 0xffff0000u), a3);
            a4 = fmaf(w2, u2f(hp2.z << 16), a4);
            a5 = fmaf(w2, u2f(hp2.z & 0xffff0000u), a5);
            a6 = fmaf(w2, u2f(hp2.w << 16), a6);
            a7 = fmaf(w2, u2f(hp2.w & 0xffff0000u), a7);
            a0 = fmaf(w3, u2f(hp3.x << 16), a0);
            a1 = fmaf(w3, u2f(hp3.x & 0xffff0000u), a1);
            a2 = fmaf(w3, u2f(hp3.y << 16), a2);
            a3 = fmaf(w3, u2f(hp3.y & 0xffff0000u), a3);
            a4 = fmaf(w3, u2f(hp3.z << 16), a4);
            a5 = fmaf(w3, u2f(hp3.z & 0xffff0000u), a5);
            a6 = fmaf(w3, u2f(hp3.w << 16), a6);
            a7 = fmaf(w3, u2f(hp3.w & 0xffff0000u), a7);
        }

        float rl = 1.0f / (l + 1e-16f);
        float4 v0, v1;
        v0.x = a0 * rl; v0.x = (v0.x > 0.f) ? v0.x : (__expf(v0.x) - 1.f);
        v0.y = a1 * rl; v0.y = (v0.y > 0.f) ? v0.y : (__expf(v0.y) - 1.f);
        v0.z = a2 * rl; v0.z = (v0.z > 0.f) ? v0.z : (__expf(v0.z) - 1.f);
        v0.w = a3 * rl; v0.w = (v0.w > 0.f) ? v0.w : (__expf(v0.w) - 1.f);
        v1.x = a4 * rl; v1.x = (v1.x > 0.f) ? v1.x : (__expf(v1.x) - 1.f);
        v1.y = a5 * rl; v1.y = (v1.y > 0.f) ? v1.y : (__expf(v1.y) - 1.f);
        v1.z = a6 * rl; v1.z = (v1.z > 0.f) ? v1.z : (__expf(v1.z) - 1.f);
        v1.w = a7 * rl; v1.w = (v1.w > 0.f) ? v1.w : (__expf(v1.w) - 1.f);
        float* op = out + ((size_t)(node_lo + node) << 6) + (q << 3);
        *(float4*)op = v0;
        *(float4*)(op + 4) = v1;
    }
}

extern "C" void kernel_launch(void* const* d_in, const int* in_sizes, int n_in,
                              void* d_out, int out_size, void* d_ws, size_t ws_size,
                              hipStream_t stream) {
    const float* x     = (const float*)d_in[0];
    const int*   ei    = (const int*)d_in[1];
    const float* W     = (const float*)d_in[2];
    const float* a_src = (const float*)d_in[3];
    const float* a_dst = (const float*)d_in[4];

    int N = in_sizes[0] / 128;
    int E = in_sizes[1] / 2;
    const int* src = ei;
    const int* dst = ei + E;
    int nb = (N + BNODES - 1) / BNODES;       // 196 buckets

    char* ws = (char*)d_ws;
    size_t off = 0;
    unsigned short* hmat = (unsigned short*)(ws + off); off += (size_t)N * 64 * 2; // 12.8 MB
    float* att_s = (float*)(ws + off);  off += (size_t)N * 4 * 4;
    float* att_d = (float*)(ws + off);  off += (size_t)N * 4 * 4;
    int* pairs    = (int*)(ws + off);   off += (size_t)nb * BCAP * 4;          // 7.2 MB
    int* pairs2   = (int*)(ws + off);   off += (size_t)nb * 64 * SCAPC * 4;    // 12.8 MB
    int* gcur     = (int*)(ws + off);   off += 256 * 4;          // zeroed by gemm blk 0
    int* scnt     = (int*)(ws + off);   off += (size_t)nb * 64 * 4; // fully written by K2b

    int gemmBlocks = (N + 63) / 64;           // 1563
    gemm_att_kernel<<<gemmBlocks, 256, 0, stream>>>(
        x, W, a_src, a_dst, hmat, att_s, att_d, gcur, N);

    int blocksS = (E + CH - 1) / CH;          // 782
    bscatter_kernel<<<blocksS, 256, 0, stream>>>(src, dst, gcur, pairs, E);

    sliceshuffle_kernel<<<nb * 8, 256, 0, stream>>>(pairs, gcur, pairs2, scnt);

    bucket_csr_agg_kernel<<<nb * 8, 256, 0, stream>>>(
        pairs2, scnt, att_s, att_d, hmat, (float*)d_out, N);
}

// Round 9
// 192.034 us; speedup vs baseline: 1.2149x; 1.0495x over previous
//
#include <hip/hip_runtime.h>

// GAT layer: N=100000 nodes, E=1.6M edges, IN=128, H=4, F=16 (H*F=64)
// fp32 in/out. 4 dispatches:
//   memset:    gcur[256] = 0 (1KB)
//   fused gemm||bscatter (round-8 lesson: gemm and bscatter have NO data
//              dependency yet ran serially at ~40us each; one dispatch,
//              blockIdx-split paths, union'd LDS (21.3KB) -> co-resident
//              overlap of MFMA-heavy gemm with LDS/scan-heavy bscatter):
//     blocks 0..781:   bscatter — LDS-staged radix partition -> packed
//              (src<<9|dstloc) ints into FIXED BCAP regions per 512-node
//              bucket; bases via one global atomicAdd(&gcur[b], cnt).
//     blocks 782..2344: gemm — h=x@W via bf16 MFMA; att = x@(W@a) folded
//              into 8 extra B-columns. h stored bf16.
//   sliceshuffle: 8 chunks/bucket = 1568 blocks x 256 thr. Single pass,
//              ballot-aggregated LDS cursors, PRIVATE per-(slice,chunk)
//              sub-regions (SCAPC=256) + scnt. Zero global atomics
//              (round-7 lesson: hot-line returning global atomics from
//              8 XCDs = 49us).
//   bucket_csr_agg: 1568 blocks (256 thr, one 64-node slice). Reads its
//              slice as 8 contiguous segments, LDS counting sort (hist+
//              scan+scatter, 2 int atomics/edge), register-accumulator
//              agg with 4-edge batching: 8-lane group per node, lane q
//              owns features 8q..8q+7 + its head's softmax denom.
//              L2-fill-BW-bound (~3 TB/s effective; hmat random gather
//              x 8 XCDs ~100MB is irreducible). No float atomics.
//              Inline exp(leakyrelu), no max-shift (softmax shift-inv,
//              |e|<~25 fp32-safe); fused normalize+ELU epilogue.

#define NEG_SLOPE 0.2f
#define BSHIFT 9            // 512 nodes per bucket
#define BNODES 512
#define CH 2048             // edges per bscatter block (16 KB LDS staging)
#define QNODES 64           // nodes per agg slice
#define BCAP 9216           // bucket region capacity: mean 8192, sd~90 (+11sd)
#define SCAP 1536           // LDS sorted[] capacity: mean 1024, sd~32 (+16sd)
#define SCAPC 256           // per-(slice,chunk) sub-region: mean 128, sd~11

typedef __bf16 bf16x8 __attribute__((ext_vector_type(8)));
typedef float  f32x4  __attribute__((ext_vector_type(4)));

static __device__ __forceinline__ unsigned f2b(float f) {
    union { float f; unsigned u; } v; v.f = f;
    return (v.u + 0x7fffu + ((v.u >> 16) & 1u)) >> 16;   // RNE
}
static __device__ __forceinline__ float u2f(unsigned u) {
    union { unsigned u32; float f; } v; v.u32 = u; return v.f;
}

// ---------------- K1: fused gemm (MFMA) || bscatter (radix partition) -----
struct SmemGemm { bf16x8 Wswz[20][64]; };                       // 20 KB
struct SmemScat {
    int cnt[256], lo[256], gpos[256], cur[256], sm[256];        // 5 KB
    int2 staged[CH];                                            // 16 KB
};
union SmemU { SmemGemm g; SmemScat s; };

__global__ __launch_bounds__(256) void fused_gemm_bscatter_kernel(
    const float* __restrict__ x,       // [N,128]
    const float* __restrict__ W,       // [128,64]
    const float* __restrict__ a_src,   // [4,16]
    const float* __restrict__ a_dst,   // [4,16]
    unsigned short* __restrict__ h_out,// bf16 [N,64]
    float* __restrict__ att_s_o,       // [N,4]
    float* __restrict__ att_d_o,       // [N,4]
    const int* __restrict__ src, const int* __restrict__ dst,
    int* __restrict__ gcur, int* __restrict__ pairs,
    int N, int E, int blocksS)
{
    __shared__ SmemU u;
    int t = threadIdx.x;

    if (blockIdx.x < blocksS) {        // ================= bscatter path ====
        int base = blockIdx.x * CH;
        int nloc = min(CH, E - base);

        u.s.cnt[t] = 0;
        __syncthreads();
        for (int i = t; i < nloc; i += 256)
            atomicAdd(&u.s.cnt[dst[base + i] >> BSHIFT], 1);
        __syncthreads();

        int v = u.s.cnt[t];
        u.s.sm[t] = v;
        __syncthreads();
        #pragma unroll
        for (int off = 1; off < 256; off <<= 1) {
            int w = (t >= off) ? u.s.sm[t - off] : 0;
            __syncthreads();
            u.s.sm[t] += w;
            __syncthreads();
        }
        u.s.lo[t] = u.s.sm[t] - v;
        u.s.cur[t] = u.s.lo[t];
        u.s.gpos[t] = (v > 0) ? t * BCAP + atomicAdd(&gcur[t], v) : 0;
        __syncthreads();

        for (int i = t; i < nloc; i += 256) {
            int d = dst[base + i];
            int s = src[base + i];
            int b = d >> BSHIFT;
            int k = atomicAdd(&u.s.cur[b], 1);
            u.s.staged[k] = make_int2((s << BSHIFT) | (d & (BNODES - 1)), b);
        }
        __syncthreads();

        for (int i = t; i < nloc; i += 256) {
            int2 p = u.s.staged[i];
            int pos = u.s.gpos[p.y] + (i - u.s.lo[p.y]);
            if (pos < (p.y + 1) * BCAP)      // capacity guard (never fires)
                pairs[pos] = p.x;
        }
        return;
    }

    // ================= gemm path =========================================
    int bid = blockIdx.x - blocksS;

    // ---- W swizzle ----
    for (int i = t; i < 8192; i += 256) {            // W[k][n], coalesced
        int k = i >> 6, n = i & 63;
        __bf16* dp = (__bf16*)&u.g.Wswz[((n >> 4) << 2) | (k >> 5)]
                                       [(((k >> 3) & 3) << 4) | (n & 15)];
        dp[k & 7] = (__bf16)W[i];
    }
    // ---- ws/wd fold: entry 16+tt, cols 0..7 = [ws|wd], cols 8..15 = 0 ----
    for (int i = t; i < 1024; i += 256) {            // k(128) x c7(8)
        int k = i >> 3, c7 = i & 7;
        int hd = c7 & 3;
        const float* aa = (c7 < 4) ? a_src : a_dst;
        float sum = 0.f;
        #pragma unroll
        for (int f = 0; f < 16; ++f)
            sum = fmaf(W[k * 64 + hd * 16 + f], aa[hd * 16 + f], sum);
        __bf16* dp = (__bf16*)&u.g.Wswz[16 + (k >> 5)][(((k >> 3) & 3) << 4) | c7];
        dp[k & 7] = (__bf16)sum;
        __bf16* dz = (__bf16*)&u.g.Wswz[16 + (k >> 5)][(((k >> 3) & 3) << 4) | (8 + c7)];
        dz[k & 7] = (__bf16)0.f;
    }
    __syncthreads();

    int wave = t >> 6;
    int lane = t & 63;
    int col = lane & 15, quad = lane >> 4;
    int node_base = (bid * 4 + wave) * 16;
    int arow = min(node_base + col, N - 1);
    const float* xp = x + arow * 128;

    bf16x8 af[4];
    #pragma unroll
    for (int tt = 0; tt < 4; ++tt) {
        float4 xa = *(const float4*)(xp + tt * 32 + quad * 8);
        float4 xb = *(const float4*)(xp + tt * 32 + quad * 8 + 4);
        bf16x8 f;
        f[0] = (__bf16)xa.x; f[1] = (__bf16)xa.y;
        f[2] = (__bf16)xa.z; f[3] = (__bf16)xa.w;
        f[4] = (__bf16)xb.x; f[5] = (__bf16)xb.y;
        f[6] = (__bf16)xb.z; f[7] = (__bf16)xb.w;
        af[tt] = f;
    }

    f32x4 acc[4], accA;
    #pragma unroll
    for (int cb = 0; cb < 4; ++cb) {
        acc[cb] = (f32x4){0.f, 0.f, 0.f, 0.f};
        #pragma unroll
        for (int tt = 0; tt < 4; ++tt)
            acc[cb] = __builtin_amdgcn_mfma_f32_16x16x32_bf16(
                af[tt], u.g.Wswz[(cb << 2) | tt][lane], acc[cb], 0, 0, 0);
    }
    accA = (f32x4){0.f, 0.f, 0.f, 0.f};
    #pragma unroll
    for (int tt = 0; tt < 4; ++tt)
        accA = __builtin_amdgcn_mfma_f32_16x16x32_bf16(
            af[tt], u.g.Wswz[16 + tt][lane], accA, 0, 0, 0);

    // h store: scalar bf16 per (cb,r)
    #pragma unroll
    for (int cb = 0; cb < 4; ++cb) {
        #pragma unroll
        for (int r = 0; r < 4; ++r) {
            int node = node_base + quad * 4 + r;
            if (node < N)
                h_out[node * 64 + cb * 16 + col] = (unsigned short)f2b(acc[cb][r]);
        }
    }
    // att store from accA: D col<4 -> att_s head=col, col 4..7 -> att_d
    if (col < 8) {
        #pragma unroll
        for (int r = 0; r < 4; ++r) {
            int node = node_base + quad * 4 + r;
            if (node < N) {
                if (col < 4) att_s_o[(node << 2) | col] = accA[r];
                else         att_d_o[(node << 2) | (col - 4)] = accA[r];
            }
        }
    }
}

// ---------------- K2b: bucket -> private (slice,chunk) sub-regions --------
// 1568 blocks x 256 thr, single pass, LDS cursors only. Per 64-edge wave
// iteration: 8 ballots; leader lane of each slice-group bumps LDS cur8
// once; rank = popc(mask & below).
__global__ __launch_bounds__(256) void sliceshuffle_kernel(
    const int* __restrict__ pairs, const int* __restrict__ gcur,
    int* __restrict__ pairs2, int* __restrict__ scnt)
{
    __shared__ int cur8[8];
    int blk = blockIdx.x, t = threadIdx.x;
    int b = blk >> 3, chunk = blk & 7;
    int cnt = min(gcur[b], BCAP);
    int clo = (cnt * chunk) >> 3;
    int chi = (cnt * (chunk + 1)) >> 3;
    int lane = t & 63;
    unsigned long long below = (lane == 0) ? 0ull : ((~0ull) >> (64 - lane));
    const int* pb = pairs + (size_t)b * BCAP;
    if (t < 8) cur8[t] = 0;
    __syncthreads();

    for (int i = clo + t; i < chi; i += 256) {
        int p = pb[i];
        int sl = (p >> 6) & 7;       // dloc bits 6..8
        int pos = 0;
        #pragma unroll
        for (int s = 0; s < 8; ++s) {
            unsigned long long m = __ballot(sl == s);
            if (sl == s) {
                int rank = __popcll(m & below);
                int b0 = 0;
                if (rank == 0) b0 = atomicAdd(&cur8[s], (int)__popcll(m));
                b0 = __shfl(b0, (int)(__ffsll((long long)m) - 1), 64);
                pos = b0 + rank;
            }
        }
        if (pos < SCAPC)
            pairs2[((size_t)((((b << 3) | sl) << 3) | chunk)) * SCAPC + pos] = p;
    }
    __syncthreads();
    if (t < 8) scnt[((((b << 3) | t) << 3) | chunk)] = min(cur8[t], SCAPC);
}

// ---------------- K3: per-slice LDS counting-sort + register agg ----------
__global__ __launch_bounds__(256, 8) void bucket_csr_agg_kernel(
    const int* __restrict__ pairs2,          // [nb*64*SCAPC] sub-regions
    const int* __restrict__ scnt,            // [nb*64] sub-region counts
    const float* __restrict__ att_s,         // [N,4]
    const float* __restrict__ att_d,         // [N,4]
    const unsigned short* __restrict__ hmat, // bf16 [N,64]
    float* __restrict__ out,                 // [N,64]
    int N)
{
    __shared__ int sorted[SCAP];             // src ids, node-sorted (6 KB)
    __shared__ int cnt[QNODES], rs[QNODES + 1], cur[QNODES], sm[QNODES];
    __shared__ int scn[8];
    __shared__ float attd[QNODES * 4];

    int blk = blockIdx.x, t = threadIdx.x;
    int b = blk >> 3, s8 = blk & 7;
    int node_lo = (b << BSHIFT) + (s8 << 6);
    if (node_lo >= N) return;
    int nn = min(QNODES, N - node_lo);

    if (t < QNODES) cnt[t] = 0;
    if (t < 8) scn[t] = scnt[(blk << 3) | t];
    // att_d for this slice -> LDS (coalesced)
    for (int i = t; i < (nn << 2); i += 256)
        attd[i] = att_d[(node_lo << 2) + i];
    __syncthreads();

    // histogram node-within-slice over 8 segments
    const int* sbase = pairs2 + ((size_t)blk << 3) * SCAPC;
    #pragma unroll
    for (int c = 0; c < 8; ++c) {
        int cn = scn[c];
        const int* seg = sbase + c * SCAPC;
        for (int i = t; i < cn; i += 256)
            atomicAdd(&cnt[seg[i] & (QNODES - 1)], 1);
    }
    __syncthreads();

    // exclusive scan (64 bins) -> rs; cur = scatter cursors
    int v = (t < QNODES) ? cnt[t] : 0;
    if (t < QNODES) sm[t] = v;
    __syncthreads();
    #pragma unroll
    for (int off = 1; off < QNODES; off <<= 1) {
        int u = (t >= off && t < QNODES) ? sm[t - off] : 0;
        __syncthreads();
        if (t < QNODES) sm[t] += u;
        __syncthreads();
    }
    if (t < QNODES) {
        int x = sm[t] - v; rs[t] = x; cur[t] = x;
        if (t == QNODES - 1) rs[QNODES] = sm[t];   // slice total
    }
    __syncthreads();

    // scatter src ids into node-sorted order (segments are L2-hot)
    #pragma unroll
    for (int c = 0; c < 8; ++c) {
        int cn = scn[c];
        const int* seg = sbase + c * SCAPC;
        for (int i = t; i < cn; i += 256) {
            int p = seg[i];
            int k = atomicAdd(&cur[p & (QNODES - 1)], 1);
            if (k < SCAP) sorted[k] = p >> BSHIFT;
        }
    }
    __syncthreads();

    // aggregate: 32 groups of 8 lanes, 2 passes over 64 nodes
    int q = t & 7;            // feature octet: features 8q..8q+7
    int h = q >> 1;           // head
    int nclamp = N - 1;       // OOB hardening (impossible SCAP overflow)

    for (int pass = 0; pass < 2; ++pass) {
        int node = (pass << 5) + (t >> 3);
        if (node >= nn) continue;
        int beg = rs[node];
        int deg = rs[node + 1] - beg;
        float ad = attd[(node << 2) | h];

        float a0 = 0.f, a1 = 0.f, a2 = 0.f, a3 = 0.f;
        float a4 = 0.f, a5 = 0.f, a6 = 0.f, a7 = 0.f, l = 0.f;
        int d1 = deg - 1;
        for (int e0 = 0; e0 < deg; e0 += 4) {
            int s0 = min(sorted[beg + min(e0 + 0, d1)], nclamp);
            int s1 = min(sorted[beg + min(e0 + 1, d1)], nclamp);
            int s2 = min(sorted[beg + min(e0 + 2, d1)], nclamp);
            int s3 = min(sorted[beg + min(e0 + 3, d1)], nclamp);
            float t0 = att_s[(s0 << 2) | h];
            float t1 = att_s[(s1 << 2) | h];
            float t2 = att_s[(s2 << 2) | h];
            float t3 = att_s[(s3 << 2) | h];
            uint4 hp0 = *(const uint4*)(hmat + (s0 << 6) + (q << 3));
            uint4 hp1 = *(const uint4*)(hmat + (s1 << 6) + (q << 3));
            uint4 hp2 = *(const uint4*)(hmat + (s2 << 6) + (q << 3));
            uint4 hp3 = *(const uint4*)(hmat + (s3 << 6) + (q << 3));
            float av0 = t0 + ad; av0 = fmaxf(av0, NEG_SLOPE * av0);
            float av1 = t1 + ad; av1 = fmaxf(av1, NEG_SLOPE * av1);
            float av2 = t2 + ad; av2 = fmaxf(av2, NEG_SLOPE * av2);
            float av3 = t3 + ad; av3 = fmaxf(av3, NEG_SLOPE * av3);
            float w0 = __expf(av0);
            float w1 = (e0 + 1 < deg) ? __expf(av1) : 0.f;
            float w2 = (e0 + 2 < deg) ? __expf(av2) : 0.f;
            float w3 = (e0 + 3 < deg) ? __expf(av3) : 0.f;
            l += w0 + w1 + w2 + w3;
            a0 = fmaf(w0, u2f(hp0.x << 16), a0);
            a1 = fmaf(w0, u2f(hp0.x & 0xffff0000u), a1);
            a2 = fmaf(w0, u2f(hp0.y << 16), a2);
            a3 = fmaf(w0, u2f(hp0.y & 0xffff0000u), a3);
            a4 = fmaf(w0, u2f(hp0.z << 16), a4);
            a5 = fmaf(w0, u2f(hp0.z & 0xffff0000u), a5);
            a6 = fmaf(w0, u2f(hp0.w << 16), a6);
            a7 = fmaf(w0, u2f(hp0.w & 0xffff0000u), a7);
            a0 = fmaf(w1, u2f(hp1.x << 16), a0);
            a1 = fmaf(w1, u2f(hp1.x & 0xffff0000u), a1);
            a2 = fmaf(w1, u2f(hp1.y << 16), a2);
            a3 = fmaf(w1, u2f(hp1.y & 0xffff0000u), a3);
            a4 = fmaf(w1, u2f(hp1.z << 16), a4);
            a5 = fmaf(w1, u2f(hp1.z & 0xffff0000u), a5);
            a6 = fmaf(w1, u2f(hp1.w << 16), a6);
            a7 = fmaf(w1, u2f(hp1.w & 0xffff0000u), a7);
            a0 = fmaf(w2, u2f(hp2.x << 16), a0);
            a1 = fmaf(w2, u2f(hp2.x & 0xffff0000u), a1);
            a2 = fmaf(w2, u2f(hp2.y << 16), a2);
            a3 = fmaf(w2, u2f(hp2.y & 0xffff0000u), a3);
            a4 = fmaf(w2, u2f(hp2.z << 16), a4);
            a5 = fmaf(w2, u2f(hp2.z & 0xffff0000u), a5);
            a6 = fmaf(w2, u2f(hp2.w << 16), a6);
            a7 = fmaf(w2, u2f(hp2.w & 0xffff0000u), a7);
            a0 = fmaf(w3, u2f(hp3.x << 16), a0);
            a1 = fmaf(w3, u2f(hp3.x & 0xffff0000u), a1);
            a2 = fmaf(w3, u2f(hp3.y << 16), a2);
            a3 = fmaf(w3, u2f(hp3.y & 0xffff0000u), a3);
            a4 = fmaf(w3, u2f(hp3.z << 16), a4);
            a5 = fmaf(w3, u2f(hp3.z & 0xffff0000u), a5);
            a6 = fmaf(w3, u2f(hp3.w << 16), a6);
            a7 = fmaf(w3, u2f(hp3.w & 0xffff0000u), a7);
        }

        float rl = 1.0f / (l + 1e-16f);
        float4 v0, v1;
        v0.x = a0 * rl; v0.x = (v0.x > 0.f) ? v0.x : (__expf(v0.x) - 1.f);
        v0.y = a1 * rl; v0.y = (v0.y > 0.f) ? v0.y : (__expf(v0.y) - 1.f);
        v0.z = a2 * rl; v0.z = (v0.z > 0.f) ? v0.z : (__expf(v0.z) - 1.f);
        v0.w = a3 * rl; v0.w = (v0.w > 0.f) ? v0.w : (__expf(v0.w) - 1.f);
        v1.x = a4 * rl; v1.x = (v1.x > 0.f) ? v1.x : (__expf(v1.x) - 1.f);
        v1.y = a5 * rl; v1.y = (v1.y > 0.f) ? v1.y : (__expf(v1.y) - 1.f);
        v1.z = a6 * rl; v1.z = (v1.z > 0.f) ? v1.z : (__expf(v1.z) - 1.f);
        v1.w = a7 * rl; v1.w = (v1.w > 0.f) ? v1.w : (__expf(v1.w) - 1.f);
        float* op = out + ((size_t)(node_lo + node) << 6) + (q << 3);
        *(float4*)op = v0;
        *(float4*)(op + 4) = v1;
    }
}

extern "C" void kernel_launch(void* const* d_in, const int* in_sizes, int n_in,
                              void* d_out, int out_size, void* d_ws, size_t ws_size,
                              hipStream_t stream) {
    const float* x     = (const float*)d_in[0];
    const int*   ei    = (const int*)d_in[1];
    const float* W     = (const float*)d_in[2];
    const float* a_src = (const float*)d_in[3];
    const float* a_dst = (const float*)d_in[4];

    int N = in_sizes[0] / 128;
    int E = in_sizes[1] / 2;
    const int* src = ei;
    const int* dst = ei + E;
    int nb = (N + BNODES - 1) / BNODES;       // 196 buckets

    char* ws = (char*)d_ws;
    size_t off = 0;
    unsigned short* hmat = (unsigned short*)(ws + off); off += (size_t)N * 64 * 2; // 12.8 MB
    float* att_s = (float*)(ws + off);  off += (size_t)N * 4 * 4;
    float* att_d = (float*)(ws + off);  off += (size_t)N * 4 * 4;
    int* pairs    = (int*)(ws + off);   off += (size_t)nb * BCAP * 4;          // 7.2 MB
    int* pairs2   = (int*)(ws + off);   off += (size_t)nb * 64 * SCAPC * 4;    // 12.8 MB
    int* gcur     = (int*)(ws + off);   off += 256 * 4;             // memset to 0
    int* scnt     = (int*)(ws + off);   off += (size_t)nb * 64 * 4; // fully written by K2b

    hipMemsetAsync(gcur, 0, 256 * 4, stream);

    int blocksS = (E + CH - 1) / CH;          // 782
    int gemmBlocks = (N + 63) / 64;           // 1563
    fused_gemm_bscatter_kernel<<<blocksS + gemmBlocks, 256, 0, stream>>>(
        x, W, a_src, a_dst, hmat, att_s, att_d,
        src, dst, gcur, pairs, N, E, blocksS);

    sliceshuffle_kernel<<<nb * 8, 256, 0, stream>>>(pairs, gcur, pairs2, scnt);

    bucket_csr_agg_kernel<<<nb * 8, 256, 0, stream>>>(
        pairs2, scnt, att_s, att_d, hmat, (float*)d_out, N);
}